// Round 11
// baseline (66.690 us; speedup 1.0000x reference)
//
#include <hip/hip_runtime.h>

#define BATCH 32
#define LATENT 128
#define NODE_DIM 8
#define MAX_NODES 512
#define H_NODE 128
#define H_EDGE 64

typedef _Float16 h2 __attribute__((ext_vector_type(2)));

static __device__ __forceinline__ h2 u32_to_h2(unsigned int x) {
    union { unsigned int u; h2 h; } c; c.u = x; return c.h;
}
static __device__ __forceinline__ unsigned int h2_to_u32(h2 x) {
    union { unsigned int u; h2 h; } c; c.h = x; return c.u;
}

#if __has_builtin(__builtin_amdgcn_fdot2)
#define FDOT2(a, b, c) __builtin_amdgcn_fdot2((a), (b), (c), false)
#else
#define FDOT2(a, b, c) ((c) + (float)(a).x * (float)(b).x + (float)(a).y * (float)(b).y)
#endif

// ws layout: UPKH u32[32][32][512] (2MB) | VH u32[32][512][32] (2MB)
//            | E2H u32[32] | Hws f32[32][128]
#define UPKH_DWORDS (BATCH * 32 * MAX_NODES)
#define VH_DWORDS   (BATCH * MAX_NODES * 32)

// ---------------------------------------------------------------------------
// Kernel 0 (unchanged): h = relu(z@W1+b1) per batch -> ws. 32 blocks.
// ---------------------------------------------------------------------------
__global__ __launch_bounds__(128) void h_gen(
    const float* __restrict__ z, const float* __restrict__ W1,
    const float* __restrict__ b1, float* __restrict__ Hws)
{
    const int b = blockIdx.x, tid = threadIdx.x;
    __shared__ float sz[LATENT];
    sz[tid] = z[b * LATENT + tid];
    __syncthreads();
    float acc = b1[tid];
#pragma unroll 8
    for (int k = 0; k < LATENT; ++k)
        acc += sz[k] * W1[k * H_NODE + tid];
    Hws[b * H_NODE + tid] = fmaxf(acc, 0.0f);
}

// ---------------------------------------------------------------------------
// Kernel 1 (unchanged): nodes (f32, d_out) + U/V packed f16 + E2 packing.
// ---------------------------------------------------------------------------
__global__ __launch_bounds__(256) void gen_nodes_uv(
    const float* __restrict__ Hws, const float* __restrict__ W2,
    const float* __restrict__ b2,  const float* __restrict__ E1,
    const float* __restrict__ eb1, const float* __restrict__ E2,
    float* __restrict__ nodes_out, unsigned int* __restrict__ UPKH,
    unsigned int* __restrict__ VH, unsigned int* __restrict__ E2H)
{
    const int b      = blockIdx.x;
    const int mslice = blockIdx.y;     // 0..15, 256 cols each
    const int tid    = threadIdx.x;    // 0..255
    const int i0     = mslice * 32;    // first node owned by this block

    __shared__ float sh[H_NODE];
    __shared__ float sE1[2 * NODE_DIM][H_EDGE];
    __shared__ float sEb1[H_EDGE];
    __shared__ float sN[32][NODE_DIM];

    if (tid < H_NODE) sh[tid] = Hws[b * H_NODE + tid];
    for (int idx = tid; idx < 2 * NODE_DIM * H_EDGE; idx += 256)
        (&sE1[0][0])[idx] = E1[idx];
    if (tid < H_EDGE) sEb1[tid] = eb1[tid];

    if (b == 0 && mslice == 0 && tid < 32) {
        h2 w = { (_Float16)E2[2 * tid], (_Float16)E2[2 * tid + 1] };
        E2H[tid] = h2_to_u32(w);
    }
    __syncthreads();

    const int m = mslice * 256 + tid;
    float acc = b2[m];
#pragma unroll 8
    for (int k = 0; k < H_NODE; ++k)
        acc += sh[k] * W2[(size_t)k * (MAX_NODES * NODE_DIM) + m];
    nodes_out[(size_t)b * (MAX_NODES * NODE_DIM) + m] = acc;
    sN[tid >> 3][tid & 7] = acc;
    __syncthreads();

    {   // U' -> f16x2, layout [b][c2][i]
        const int il = tid & 31;
        const int cg = tid >> 5;
#pragma unroll
        for (int rep = 0; rep < 4; ++rep) {
            const int c2 = rep * 8 + cg;
            const int c  = 2 * c2;
            float ua = sEb1[c], ub = sEb1[c + 1];
#pragma unroll
            for (int d = 0; d < NODE_DIM; ++d) {
                const float nd = sN[il][d];
                ua += nd * sE1[d][c];
                ub += nd * sE1[d][c + 1];
            }
            h2 uu = { (_Float16)ua, (_Float16)ub };
            UPKH[((size_t)b * 32 + c2) * MAX_NODES + i0 + il] = h2_to_u32(uu);
        }
    }
    {   // V' -> f16x2, layout [b][j][c2] (128B rows)
        const int jl = tid >> 3;
        const int cq = tid & 7;
#pragma unroll
        for (int rep = 0; rep < 4; ++rep) {
            const int c2 = rep * 8 + cq;
            const int c  = 2 * c2;
            float va = 0.f, vb = 0.f;
#pragma unroll
            for (int d = 0; d < NODE_DIM; ++d) {
                const float nd = sN[jl][d];
                va += nd * sE1[NODE_DIM + d][c];
                vb += nd * sE1[NODE_DIM + d][c + 1];
            }
            h2 vv = { (_Float16)va, (_Float16)vb };
            VH[((size_t)(b * MAX_NODES + i0 + jl) << 5) + c2] = h2_to_u32(vv);
        }
    }
}

// ---------------------------------------------------------------------------
// Kernel 2: edge probabilities + adjacency.
// Tile 64 i x 16 j (144 tiles/batch -> 4608 blocks, 2x R10 parallelism).
// Block = 256 thr (4 waves); lane owns i; wave wv owns j's jl = wv*4+{0..3},
// processed JOINTLY in one channel sweep: per q-step 4 uniform ds_read_b128
// feed 48 independent pk/dot ops (ds:VALU 1:12, 4-way ILP). One sigmoid
// group per tile. VGPR ~80 -> 6 waves/SIMD; LDS 6.2 KB.
// Tiles: jt in 4*bi..31; partial iff (jt>>2)==bi.
// ---------------------------------------------------------------------------
__global__ __launch_bounds__(256, 4) void edge_gen(
    const unsigned int* __restrict__ UPKH, const unsigned int* __restrict__ VH,
    const unsigned int* __restrict__ E2H, const float* __restrict__ eb2,
    float* __restrict__ adj)
{
    const int b = blockIdx.y;
    // decode tile: bi in 0..7 (64-wide i), jt in 4*bi..31 (16-wide j)
    int t = blockIdx.x, bi = 0;
    while (t >= 32 - 4 * bi) { t -= 32 - 4 * bi; ++bi; }
    const int jt = 4 * bi + t;
    const bool partial = (jt >> 2) == bi;    // j-window inside i-block

    const int tid  = threadIdx.x;
    const int lane = tid & 63;
    const int wv   = tid >> 6;               // 0..3
    const int i0 = bi * 64, j0 = jt * 16;
    const int i  = i0 + lane;

    __shared__ unsigned int sV[16 * 32];     // 16 rows x 64ch f16 = 2 KB
    __shared__ float P[16][65];              // tile probs for mirror (4.2 KB)

    // stage V tile: 2 KB contiguous, threads 0..127 load one uint4 each
    if (tid < 128) {
        const uint4* src = (const uint4*)(VH + ((size_t)(b * MAX_NODES + j0) << 5));
        ((uint4*)sV)[tid] = src[tid];
    }

    // U row for this lane: 32 f16x2 dwords, coalesced per c2
    unsigned int uA[32];
#pragma unroll
    for (int c2 = 0; c2 < 32; ++c2)
        uA[c2] = UPKH[((size_t)b * 32 + c2) * MAX_NODES + i];

    // E2 packed f16x2: 32 uniform dword loads (SGPR path)
    unsigned int wb[32];
#pragma unroll
    for (int c2 = 0; c2 < 32; ++c2) wb[c2] = E2H[c2];

    const float bias = eb2[0];
    float* adjb = adj + (size_t)b * MAX_NODES * MAX_NODES;
    const h2 zh = { (_Float16)0.f, (_Float16)0.f };
    __syncthreads();

    const int jbase = wv * 4;                // this wave's 4 j's
    const uint4* vr0 = (const uint4*)&sV[(jbase + 0) * 32];
    const uint4* vr1 = (const uint4*)&sV[(jbase + 1) * 32];
    const uint4* vr2 = (const uint4*)&sV[(jbase + 2) * 32];
    const uint4* vr3 = (const uint4*)&sV[(jbase + 3) * 32];

    float acc0a = 0.f, acc0b = 0.f, acc1a = 0.f, acc1b = 0.f;
    float acc2a = 0.f, acc2b = 0.f, acc3a = 0.f, acc3b = 0.f;

#pragma unroll
    for (int q = 0; q < 8; ++q) {
        union { uint4 u4; unsigned int u[4]; } v0, v1, v2, v3;
        v0.u4 = vr0[q]; v1.u4 = vr1[q]; v2.u4 = vr2[q]; v3.u4 = vr3[q];
#pragma unroll
        for (int k = 0; k < 4; ++k) {
            const int c2 = 4 * q + k;
            const h2 u = u32_to_h2(uA[c2]);
            const h2 w = u32_to_h2(wb[c2]);
            h2 s0 = u + u32_to_h2(v0.u[k]);
            h2 s1 = u + u32_to_h2(v1.u[k]);
            h2 s2 = u + u32_to_h2(v2.u[k]);
            h2 s3 = u + u32_to_h2(v3.u[k]);
            s0 = __builtin_elementwise_max(s0, zh);
            s1 = __builtin_elementwise_max(s1, zh);
            s2 = __builtin_elementwise_max(s2, zh);
            s3 = __builtin_elementwise_max(s3, zh);
            if (k & 1) {
                acc0b = FDOT2(s0, w, acc0b); acc1b = FDOT2(s1, w, acc1b);
                acc2b = FDOT2(s2, w, acc2b); acc3b = FDOT2(s3, w, acc3b);
            } else {
                acc0a = FDOT2(s0, w, acc0a); acc1a = FDOT2(s1, w, acc1a);
                acc2a = FDOT2(s2, w, acc2a); acc3a = FDOT2(s3, w, acc3a);
            }
        }
    }

    float px[4];
    px[0] = acc0a + acc0b + bias;
    px[1] = acc1a + acc1b + bias;
    px[2] = acc2a + acc2b + bias;
    px[3] = acc3a + acc3b + bias;
#pragma unroll
    for (int jj = 0; jj < 4; ++jj)
        px[jj] = __builtin_amdgcn_rcpf(1.0f + __expf(-px[jj]));

#pragma unroll
    for (int jj = 0; jj < 4; ++jj) {
        const int jl = jbase + jj;
        const int j  = j0 + jl;
        const float p = px[jj];
        if (!partial) {
            adjb[(size_t)j * MAX_NODES + i] = p;     // lower half, coalesced
            P[jl][lane] = p;                         // stage for mirror
        } else {
            if (i < j)       { adjb[(size_t)j * MAX_NODES + i] = p;
                               adjb[(size_t)i * MAX_NODES + j] = p; }
            else if (i == j)   adjb[(size_t)j * MAX_NODES + i] = 0.0f;
        }
    }

    if (!partial) {
        __syncthreads();
        // mirror: adj[i0+r][j0..j0+15]; thread owns row r = tid&63, quarter q
        const int r = tid & 63;
        const int q = tid >> 6;              // 0..3
        float4 o;
        o.x = P[q * 4 + 0][r]; o.y = P[q * 4 + 1][r];
        o.z = P[q * 4 + 2][r]; o.w = P[q * 4 + 3][r];
        *(float4*)&adjb[(size_t)(i0 + r) * MAX_NODES + j0 + q * 4] = o;
    }
}

// ---------------------------------------------------------------------------
extern "C" void kernel_launch(void* const* d_in, const int* in_sizes, int n_in,
                              void* d_out, int out_size, void* d_ws, size_t ws_size,
                              hipStream_t stream)
{
    const float* z   = (const float*)d_in[0];
    const float* W1  = (const float*)d_in[1];
    const float* b1  = (const float*)d_in[2];
    const float* W2  = (const float*)d_in[3];
    const float* b2  = (const float*)d_in[4];
    const float* E1  = (const float*)d_in[5];
    const float* eb1 = (const float*)d_in[6];
    const float* E2  = (const float*)d_in[7];
    const float* eb2 = (const float*)d_in[8];

    float* nodes_out = (float*)d_out;                                   // [32,512,8]
    float* adj       = (float*)d_out + BATCH * MAX_NODES * NODE_DIM;    // [32,512,512]

    unsigned int* UPKH = (unsigned int*)d_ws;       // 2 MB
    unsigned int* VHp  = UPKH + UPKH_DWORDS;        // 2 MB
    unsigned int* E2H  = VHp + VH_DWORDS;           // 128 B
    float*        Hws  = (float*)(E2H + 32);        // 16 KB

    h_gen<<<BATCH, 128, 0, stream>>>(z, W1, b1, Hws);

    dim3 g1(BATCH, 16);
    gen_nodes_uv<<<g1, 256, 0, stream>>>(Hws, W2, b2, E1, eb1, E2,
                                         nodes_out, UPKH, VHp, E2H);

    dim3 g2(144, BATCH);
    edge_gen<<<g2, 256, 0, stream>>>(UPKH, VHp, E2H, eb2, adj);
}

// Round 12
// 53.954 us; speedup vs baseline: 1.2361x; 1.2361x over previous
//
#include <hip/hip_runtime.h>

#define BATCH 32
#define LATENT 128
#define NODE_DIM 8
#define MAX_NODES 512
#define H_NODE 128
#define H_EDGE 64

typedef _Float16 h2 __attribute__((ext_vector_type(2)));

static __device__ __forceinline__ h2 u32_to_h2(unsigned int x) {
    union { unsigned int u; h2 h; } c; c.u = x; return c.h;
}
static __device__ __forceinline__ unsigned int h2_to_u32(h2 x) {
    union { unsigned int u; h2 h; } c; c.h = x; return c.u;
}

#if __has_builtin(__builtin_amdgcn_fdot2)
#define FDOT2(a, b, c) __builtin_amdgcn_fdot2((a), (b), (c), false)
#else
#define FDOT2(a, b, c) ((c) + (float)(a).x * (float)(b).x + (float)(a).y * (float)(b).y)
#endif

// ws layout: UPKH u32[32][32][512] (2MB) | VH u32[32][512][32] (2MB)
//            | E2H u32[32] | Hws f32[32][128]
#define UPKH_DWORDS (BATCH * 32 * MAX_NODES)
#define VH_DWORDS   (BATCH * MAX_NODES * 32)

// ---------------------------------------------------------------------------
// Kernel 0 (unchanged): h = relu(z@W1+b1) per batch -> ws. 32 blocks.
// ---------------------------------------------------------------------------
__global__ __launch_bounds__(128) void h_gen(
    const float* __restrict__ z, const float* __restrict__ W1,
    const float* __restrict__ b1, float* __restrict__ Hws)
{
    const int b = blockIdx.x, tid = threadIdx.x;
    __shared__ float sz[LATENT];
    sz[tid] = z[b * LATENT + tid];
    __syncthreads();
    float acc = b1[tid];
#pragma unroll 8
    for (int k = 0; k < LATENT; ++k)
        acc += sz[k] * W1[k * H_NODE + tid];
    Hws[b * H_NODE + tid] = fmaxf(acc, 0.0f);
}

// ---------------------------------------------------------------------------
// Kernel 1 (unchanged): nodes (f32, d_out) + U/V packed f16 + E2 packing.
// ---------------------------------------------------------------------------
__global__ __launch_bounds__(256) void gen_nodes_uv(
    const float* __restrict__ Hws, const float* __restrict__ W2,
    const float* __restrict__ b2,  const float* __restrict__ E1,
    const float* __restrict__ eb1, const float* __restrict__ E2,
    float* __restrict__ nodes_out, unsigned int* __restrict__ UPKH,
    unsigned int* __restrict__ VH, unsigned int* __restrict__ E2H)
{
    const int b      = blockIdx.x;
    const int mslice = blockIdx.y;     // 0..15, 256 cols each
    const int tid    = threadIdx.x;    // 0..255
    const int i0     = mslice * 32;    // first node owned by this block

    __shared__ float sh[H_NODE];
    __shared__ float sE1[2 * NODE_DIM][H_EDGE];
    __shared__ float sEb1[H_EDGE];
    __shared__ float sN[32][NODE_DIM];

    if (tid < H_NODE) sh[tid] = Hws[b * H_NODE + tid];
    for (int idx = tid; idx < 2 * NODE_DIM * H_EDGE; idx += 256)
        (&sE1[0][0])[idx] = E1[idx];
    if (tid < H_EDGE) sEb1[tid] = eb1[tid];

    if (b == 0 && mslice == 0 && tid < 32) {
        h2 w = { (_Float16)E2[2 * tid], (_Float16)E2[2 * tid + 1] };
        E2H[tid] = h2_to_u32(w);
    }
    __syncthreads();

    const int m = mslice * 256 + tid;
    float acc = b2[m];
#pragma unroll 8
    for (int k = 0; k < H_NODE; ++k)
        acc += sh[k] * W2[(size_t)k * (MAX_NODES * NODE_DIM) + m];
    nodes_out[(size_t)b * (MAX_NODES * NODE_DIM) + m] = acc;
    sN[tid >> 3][tid & 7] = acc;
    __syncthreads();

    {   // U' -> f16x2, layout [b][c2][i]
        const int il = tid & 31;
        const int cg = tid >> 5;
#pragma unroll
        for (int rep = 0; rep < 4; ++rep) {
            const int c2 = rep * 8 + cg;
            const int c  = 2 * c2;
            float ua = sEb1[c], ub = sEb1[c + 1];
#pragma unroll
            for (int d = 0; d < NODE_DIM; ++d) {
                const float nd = sN[il][d];
                ua += nd * sE1[d][c];
                ub += nd * sE1[d][c + 1];
            }
            h2 uu = { (_Float16)ua, (_Float16)ub };
            UPKH[((size_t)b * 32 + c2) * MAX_NODES + i0 + il] = h2_to_u32(uu);
        }
    }
    {   // V' -> f16x2, layout [b][j][c2] (128B rows)
        const int jl = tid >> 3;
        const int cq = tid & 7;
#pragma unroll
        for (int rep = 0; rep < 4; ++rep) {
            const int c2 = rep * 8 + cq;
            const int c  = 2 * c2;
            float va = 0.f, vb = 0.f;
#pragma unroll
            for (int d = 0; d < NODE_DIM; ++d) {
                const float nd = sN[jl][d];
                va += nd * sE1[NODE_DIM + d][c];
                vb += nd * sE1[NODE_DIM + d][c + 1];
            }
            h2 vv = { (_Float16)va, (_Float16)vb };
            VH[((size_t)(b * MAX_NODES + i0 + jl) << 5) + c2] = h2_to_u32(vv);
        }
    }
}

// ---------------------------------------------------------------------------
// Channel sweep: 64-ch f16 dot for one (i, j) pair. Fully unrolled, static
// register indices (uA stays in VGPRs, wb in SGPRs).
// ---------------------------------------------------------------------------
static __device__ __forceinline__ float edge_dot(
    const uint4* vrow, const unsigned int (&uA)[32], const unsigned int (&wb)[32])
{
    const h2 zh = { (_Float16)0.f, (_Float16)0.f };
    float a0 = 0.f, a1 = 0.f;
#pragma unroll
    for (int q = 0; q < 8; ++q) {
        union { uint4 u4; unsigned int u[4]; } vv;
        vv.u4 = vrow[q];                 // ds_read_b128, wave-uniform
#pragma unroll
        for (int k = 0; k < 4; ++k) {
            const int c2 = 4 * q + k;
            const h2 v = u32_to_h2(vv.u[k]);
            const h2 w = u32_to_h2(wb[c2]);
            h2 s = u32_to_h2(uA[c2]) + v;
            s = __builtin_elementwise_max(s, zh);
            if (k & 1) a1 = FDOT2(s, w, a1);
            else       a0 = FDOT2(s, w, a0);
        }
    }
    return a0 + a1;
}

// ---------------------------------------------------------------------------
// Kernel 2: edge probabilities + adjacency. ZERO scattered writes.
// 64 tiles/batch: x<8 -> diagonal 64x64 tile bi=x (compute all orientations,
// write full 256B rows with in-register select); x>=8 -> off-diagonal 64x32
// tile (strict i<j: unpredicated direct write + LDS-transpose mirror).
// All adj bytes written exactly once, full aligned lines.
// ---------------------------------------------------------------------------
__global__ __launch_bounds__(256, 4) void edge_gen(
    const unsigned int* __restrict__ UPKH, const unsigned int* __restrict__ VH,
    const unsigned int* __restrict__ E2H, const float* __restrict__ eb2,
    float* __restrict__ adj)
{
    const int b = blockIdx.y;
    const int x = blockIdx.x;                // 0..63
    const int tid  = threadIdx.x;
    const int lane = tid & 63;
    const int wv   = tid >> 6;               // 0..3

    __shared__ unsigned int sV[64 * 32];     // up to 64 V rows (8 KB)
    __shared__ float P[64][65];              // up to 64x64 probs (16.6 KB)

    int bi, j0, nj;
    if (x < 8) { bi = x; j0 = bi * 64; nj = 64; }          // diagonal tile
    else {
        int k = x - 8; bi = 0;
        while (k >= 14 - 2 * bi) { k -= 14 - 2 * bi; ++bi; }
        j0 = (2 * bi + 2 + k) * 32; nj = 32;               // off-diagonal
    }
    const int i0 = bi * 64;
    const int i  = i0 + lane;

    // stage V rows [j0, j0+nj): contiguous, full lines
    {
        const uint4* src = (const uint4*)(VH + ((size_t)(b * MAX_NODES + j0) << 5));
        uint4* dst = (uint4*)sV;
        dst[tid] = src[tid];                 // 256 uint4 = 32 rows
        if (nj == 64) dst[tid + 256] = src[tid + 256];
    }

    // U row for this lane: 32 f16x2 dwords, coalesced per c2
    unsigned int uA[32];
#pragma unroll
    for (int c2 = 0; c2 < 32; ++c2)
        uA[c2] = UPKH[((size_t)b * 32 + c2) * MAX_NODES + i];

    // E2 packed f16x2: 32 uniform dword loads (SGPR path)
    unsigned int wb[32];
#pragma unroll
    for (int c2 = 0; c2 < 32; ++c2) wb[c2] = E2H[c2];

    const float bias = eb2[0];
    float* adjb = adj + (size_t)b * MAX_NODES * MAX_NODES;
    __syncthreads();

    if (nj == 32) {
        // ---- off-diagonal 64x32: i < j everywhere ----
#pragma unroll 1
        for (int jj = 0; jj < 8; ++jj) {
            const int jl = wv * 8 + jj;      // 0..31
            const int j  = j0 + jl;
            const float xs = edge_dot((const uint4*)&sV[jl * 32], uA, wb) + bias;
            const float p  = __builtin_amdgcn_rcpf(1.0f + __expf(-xs));
            adjb[(size_t)j * MAX_NODES + i] = p;     // lower half, 256B/wave
            P[jl][lane] = p;                         // stage for mirror
        }
        __syncthreads();
        // mirror: adj[i0+r][j0..j0+31]
        const int r = tid & 63;
        const int q = tid >> 6;              // 0..3, 8 cols each
        const size_t rowbase = (size_t)(i0 + r) * MAX_NODES + j0 + q * 8;
        float4 o0, o1;
        o0.x = P[q * 8 + 0][r]; o0.y = P[q * 8 + 1][r];
        o0.z = P[q * 8 + 2][r]; o0.w = P[q * 8 + 3][r];
        o1.x = P[q * 8 + 4][r]; o1.y = P[q * 8 + 5][r];
        o1.z = P[q * 8 + 6][r]; o1.w = P[q * 8 + 7][r];
        *(float4*)&adjb[rowbase]     = o0;
        *(float4*)&adjb[rowbase + 4] = o1;
    } else {
        // ---- diagonal 64x64: compute all orientations, row-select write ----
#pragma unroll 1
        for (int jj = 0; jj < 16; ++jj) {
            const int jl = wv * 16 + jj;     // 0..63
            const float xs = edge_dot((const uint4*)&sV[jl * 32], uA, wb) + bias;
            P[jl][lane] = __builtin_amdgcn_rcpf(1.0f + __expf(-xs));
        }
        __syncthreads();
        // write full rows: adj[i0+r][i0+c] = r<c ? P[c][r] : (r>c ? P[r][c] : 0)
        const int r = tid & 63;
        const int q = tid >> 6;              // 0..3, 16 cols each
#pragma unroll
        for (int g = 0; g < 4; ++g) {
            const int cb = q * 16 + g * 4;
            float4 o;
            {
                const int c = cb + 0;
                o.x = (r < c) ? P[c][r] : ((r > c) ? P[r][c] : 0.0f);
            }
            {
                const int c = cb + 1;
                o.y = (r < c) ? P[c][r] : ((r > c) ? P[r][c] : 0.0f);
            }
            {
                const int c = cb + 2;
                o.z = (r < c) ? P[c][r] : ((r > c) ? P[r][c] : 0.0f);
            }
            {
                const int c = cb + 3;
                o.w = (r < c) ? P[c][r] : ((r > c) ? P[r][c] : 0.0f);
            }
            *(float4*)&adjb[(size_t)(i0 + r) * MAX_NODES + i0 + cb] = o;
        }
    }
}

// ---------------------------------------------------------------------------
extern "C" void kernel_launch(void* const* d_in, const int* in_sizes, int n_in,
                              void* d_out, int out_size, void* d_ws, size_t ws_size,
                              hipStream_t stream)
{
    const float* z   = (const float*)d_in[0];
    const float* W1  = (const float*)d_in[1];
    const float* b1  = (const float*)d_in[2];
    const float* W2  = (const float*)d_in[3];
    const float* b2  = (const float*)d_in[4];
    const float* E1  = (const float*)d_in[5];
    const float* eb1 = (const float*)d_in[6];
    const float* E2  = (const float*)d_in[7];
    const float* eb2 = (const float*)d_in[8];

    float* nodes_out = (float*)d_out;                                   // [32,512,8]
    float* adj       = (float*)d_out + BATCH * MAX_NODES * NODE_DIM;    // [32,512,512]

    unsigned int* UPKH = (unsigned int*)d_ws;       // 2 MB
    unsigned int* VHp  = UPKH + UPKH_DWORDS;        // 2 MB
    unsigned int* E2H  = VHp + VH_DWORDS;           // 128 B
    float*        Hws  = (float*)(E2H + 32);        // 16 KB

    h_gen<<<BATCH, 128, 0, stream>>>(z, W1, b1, Hws);

    dim3 g1(BATCH, 16);
    gen_nodes_uv<<<g1, 256, 0, stream>>>(Hws, W2, b2, E1, eb1, E2,
                                         nodes_out, UPKH, VHp, E2H);

    dim3 g2(64, BATCH);
    edge_gen<<<g2, 256, 0, stream>>>(UPKH, VHp, E2H, eb2, adj);
}

// Round 13
// 48.913 us; speedup vs baseline: 1.3635x; 1.1031x over previous
//
#include <hip/hip_runtime.h>

#define BATCH 32
#define LATENT 128
#define NODE_DIM 8
#define MAX_NODES 512
#define H_NODE 128
#define H_EDGE 64

typedef _Float16 h2 __attribute__((ext_vector_type(2)));

static __device__ __forceinline__ h2 u32_to_h2(unsigned int x) {
    union { unsigned int u; h2 h; } c; c.u = x; return c.h;
}
static __device__ __forceinline__ unsigned int h2_to_u32(h2 x) {
    union { unsigned int u; h2 h; } c; c.h = x; return c.u;
}

#if __has_builtin(__builtin_amdgcn_fdot2)
#define FDOT2(a, b, c) __builtin_amdgcn_fdot2((a), (b), (c), false)
#else
#define FDOT2(a, b, c) ((c) + (float)(a).x * (float)(b).x + (float)(a).y * (float)(b).y)
#endif

// ws layout: UPKH u32[32][32][512] (2MB) | VH u32[32][512][32] (2MB)
//            | E2H u32[32] | Hws f32[32][128]
#define UPKH_DWORDS (BATCH * 32 * MAX_NODES)
#define VH_DWORDS   (BATCH * MAX_NODES * 32)

// ---------------------------------------------------------------------------
// Kernel 0 (unchanged): h = relu(z@W1+b1) per batch -> ws. 32 blocks.
// ---------------------------------------------------------------------------
__global__ __launch_bounds__(128) void h_gen(
    const float* __restrict__ z, const float* __restrict__ W1,
    const float* __restrict__ b1, float* __restrict__ Hws)
{
    const int b = blockIdx.x, tid = threadIdx.x;
    __shared__ float sz[LATENT];
    sz[tid] = z[b * LATENT + tid];
    __syncthreads();
    float acc = b1[tid];
#pragma unroll 8
    for (int k = 0; k < LATENT; ++k)
        acc += sz[k] * W1[k * H_NODE + tid];
    Hws[b * H_NODE + tid] = fmaxf(acc, 0.0f);
}

// ---------------------------------------------------------------------------
// Kernel 1 (unchanged): nodes (f32, d_out) + U/V packed f16 + E2 packing.
// ---------------------------------------------------------------------------
__global__ __launch_bounds__(256) void gen_nodes_uv(
    const float* __restrict__ Hws, const float* __restrict__ W2,
    const float* __restrict__ b2,  const float* __restrict__ E1,
    const float* __restrict__ eb1, const float* __restrict__ E2,
    float* __restrict__ nodes_out, unsigned int* __restrict__ UPKH,
    unsigned int* __restrict__ VH, unsigned int* __restrict__ E2H)
{
    const int b      = blockIdx.x;
    const int mslice = blockIdx.y;     // 0..15, 256 cols each
    const int tid    = threadIdx.x;    // 0..255
    const int i0     = mslice * 32;    // first node owned by this block

    __shared__ float sh[H_NODE];
    __shared__ float sE1[2 * NODE_DIM][H_EDGE];
    __shared__ float sEb1[H_EDGE];
    __shared__ float sN[32][NODE_DIM];

    if (tid < H_NODE) sh[tid] = Hws[b * H_NODE + tid];
    for (int idx = tid; idx < 2 * NODE_DIM * H_EDGE; idx += 256)
        (&sE1[0][0])[idx] = E1[idx];
    if (tid < H_EDGE) sEb1[tid] = eb1[tid];

    if (b == 0 && mslice == 0 && tid < 32) {
        h2 w = { (_Float16)E2[2 * tid], (_Float16)E2[2 * tid + 1] };
        E2H[tid] = h2_to_u32(w);
    }
    __syncthreads();

    const int m = mslice * 256 + tid;
    float acc = b2[m];
#pragma unroll 8
    for (int k = 0; k < H_NODE; ++k)
        acc += sh[k] * W2[(size_t)k * (MAX_NODES * NODE_DIM) + m];
    nodes_out[(size_t)b * (MAX_NODES * NODE_DIM) + m] = acc;
    sN[tid >> 3][tid & 7] = acc;
    __syncthreads();

    {   // U' -> f16x2, layout [b][c2][i]
        const int il = tid & 31;
        const int cg = tid >> 5;
#pragma unroll
        for (int rep = 0; rep < 4; ++rep) {
            const int c2 = rep * 8 + cg;
            const int c  = 2 * c2;
            float ua = sEb1[c], ub = sEb1[c + 1];
#pragma unroll
            for (int d = 0; d < NODE_DIM; ++d) {
                const float nd = sN[il][d];
                ua += nd * sE1[d][c];
                ub += nd * sE1[d][c + 1];
            }
            h2 uu = { (_Float16)ua, (_Float16)ub };
            UPKH[((size_t)b * 32 + c2) * MAX_NODES + i0 + il] = h2_to_u32(uu);
        }
    }
    {   // V' -> f16x2, layout [b][j][c2] (128B rows)
        const int jl = tid >> 3;
        const int cq = tid & 7;
#pragma unroll
        for (int rep = 0; rep < 4; ++rep) {
            const int c2 = rep * 8 + cq;
            const int c  = 2 * c2;
            float va = 0.f, vb = 0.f;
#pragma unroll
            for (int d = 0; d < NODE_DIM; ++d) {
                const float nd = sN[jl][d];
                va += nd * sE1[NODE_DIM + d][c];
                vb += nd * sE1[NODE_DIM + d][c + 1];
            }
            h2 vv = { (_Float16)va, (_Float16)vb };
            VH[((size_t)(b * MAX_NODES + i0 + jl) << 5) + c2] = h2_to_u32(vv);
        }
    }
}

// ---------------------------------------------------------------------------
// 64-channel f16 dot from a REGISTER-resident V row (8 uint4). 4 acc chains.
// ---------------------------------------------------------------------------
static __device__ __forceinline__ float edge_dot_regs(
    const uint4 (&v)[8], const unsigned int (&uA)[32], const unsigned int (&wb)[32])
{
    const h2 zh = { (_Float16)0.f, (_Float16)0.f };
    float a0 = 0.f, a1 = 0.f, a2 = 0.f, a3 = 0.f;
#pragma unroll
    for (int q = 0; q < 8; ++q) {
        union { uint4 u4; unsigned int u[4]; } vv;
        vv.u4 = v[q];
        {
            const int c2 = 4 * q + 0;
            h2 s = u32_to_h2(uA[c2]) + u32_to_h2(vv.u[0]);
            s = __builtin_elementwise_max(s, zh);
            a0 = FDOT2(s, u32_to_h2(wb[c2]), a0);
        }
        {
            const int c2 = 4 * q + 1;
            h2 s = u32_to_h2(uA[c2]) + u32_to_h2(vv.u[1]);
            s = __builtin_elementwise_max(s, zh);
            a1 = FDOT2(s, u32_to_h2(wb[c2]), a1);
        }
        {
            const int c2 = 4 * q + 2;
            h2 s = u32_to_h2(uA[c2]) + u32_to_h2(vv.u[2]);
            s = __builtin_elementwise_max(s, zh);
            a2 = FDOT2(s, u32_to_h2(wb[c2]), a2);
        }
        {
            const int c2 = 4 * q + 3;
            h2 s = u32_to_h2(uA[c2]) + u32_to_h2(vv.u[3]);
            s = __builtin_elementwise_max(s, zh);
            a3 = FDOT2(s, u32_to_h2(wb[c2]), a3);
        }
    }
    return (a0 + a1) + (a2 + a3);
}

// ---------------------------------------------------------------------------
// Kernel 2: edge probabilities + adjacency. R10 geometry (72 tiles/batch,
// 64 i x 32 j, measured best) with a SOFTWARE-PIPELINED jj loop: V row for
// jj+1 is loaded into the alternate register buffer while jj computes, so
// LDS latency is hidden intra-wave (the R4-R12 `unroll 1` loops exposed
// ~120-200 cyc per jj -> VALUBusy ~50%). Two jj per pipeline step, named
// double buffers (static indexing), 4 acc chains.
// ---------------------------------------------------------------------------
__global__ __launch_bounds__(256, 3) void edge_gen(
    const unsigned int* __restrict__ UPKH, const unsigned int* __restrict__ VH,
    const unsigned int* __restrict__ E2H, const float* __restrict__ eb2,
    float* __restrict__ adj)
{
    const int b = blockIdx.y;
    // decode tile: bi in 0..7 (64-wide i), jt in 2*bi..15 (32-wide j)
    int t = blockIdx.x, bi = 0;
    while (t >= 16 - 2 * bi) { t -= 16 - 2 * bi; ++bi; }
    const int jt = 2 * bi + t;
    const bool partial = (jt >> 1) == bi;    // j-window inside i-block

    const int tid  = threadIdx.x;
    const int lane = tid & 63;
    const int wv   = tid >> 6;               // 0..3
    const int i0 = bi * 64, j0 = jt * 32;
    const int i  = i0 + lane;

    __shared__ unsigned int sV[32 * 32];     // 32 rows x 64ch f16 = 4 KB
    __shared__ float P[32][65];              // tile probs for mirror (8.3 KB)

    // stage V tile: 4 KB contiguous, 1 uint4 per thread
    {
        const uint4* src = (const uint4*)(VH + ((size_t)(b * MAX_NODES + j0) << 5));
        ((uint4*)sV)[tid] = src[tid];
    }

    // U row for this lane: 32 f16x2 dwords, coalesced per c2
    unsigned int uA[32];
#pragma unroll
    for (int c2 = 0; c2 < 32; ++c2)
        uA[c2] = UPKH[((size_t)b * 32 + c2) * MAX_NODES + i];

    // E2 packed f16x2: 32 uniform dword loads (SGPR path)
    unsigned int wb[32];
#pragma unroll
    for (int c2 = 0; c2 < 32; ++c2) wb[c2] = E2H[c2];

    const float bias = eb2[0];
    float* adjb = adj + (size_t)b * MAX_NODES * MAX_NODES;
    __syncthreads();

    // this wave's 8 V rows, as 8 uint4 each
    const uint4* vbase = (const uint4*)&sV[(wv * 8) * 32];

    uint4 va[8], vb_[8];
#pragma unroll
    for (int q = 0; q < 8; ++q) va[q] = vbase[q];        // prefetch row 0

#pragma unroll 1
    for (int jp = 0; jp < 4; ++jp) {                     // 2 jj per step
        const int jlA = wv * 8 + 2 * jp;
        const int jlB = jlA + 1;

        // issue B-row loads; they complete under compute-A
#pragma unroll
        for (int q = 0; q < 8; ++q) vb_[q] = vbase[(2 * jp + 1) * 8 + q];

        const float xA = edge_dot_regs(va, uA, wb) + bias;

        // issue next A-row loads; they complete under compute-B
        if (jp < 3) {
#pragma unroll
            for (int q = 0; q < 8; ++q) va[q] = vbase[(2 * jp + 2) * 8 + q];
        }

        const float xB = edge_dot_regs(vb_, uA, wb) + bias;

        const float pA = __builtin_amdgcn_rcpf(1.0f + __expf(-xA));
        const float pB = __builtin_amdgcn_rcpf(1.0f + __expf(-xB));

        const int jA = j0 + jlA, jB = j0 + jlB;
        if (!partial) {
            adjb[(size_t)jA * MAX_NODES + i] = pA;       // lower half, coalesced
            adjb[(size_t)jB * MAX_NODES + i] = pB;
            P[jlA][lane] = pA;                           // stage for mirror
            P[jlB][lane] = pB;
        } else {
            if (i < jA)       { adjb[(size_t)jA * MAX_NODES + i] = pA;
                                adjb[(size_t)i * MAX_NODES + jA] = pA; }
            else if (i == jA)   adjb[(size_t)jA * MAX_NODES + i] = 0.0f;
            if (i < jB)       { adjb[(size_t)jB * MAX_NODES + i] = pB;
                                adjb[(size_t)i * MAX_NODES + jB] = pB; }
            else if (i == jB)   adjb[(size_t)jB * MAX_NODES + i] = 0.0f;
        }
    }

    if (!partial) {
        __syncthreads();
        // mirror: adj[i0+r][j0..j0+31]; thread owns row r = tid&63, quarter q
        const int r = tid & 63;
        const int q = tid >> 6;              // 0..3
        const size_t rowbase = (size_t)(i0 + r) * MAX_NODES + j0 + q * 8;
        float4 o0, o1;
        o0.x = P[q * 8 + 0][r]; o0.y = P[q * 8 + 1][r];
        o0.z = P[q * 8 + 2][r]; o0.w = P[q * 8 + 3][r];
        o1.x = P[q * 8 + 4][r]; o1.y = P[q * 8 + 5][r];
        o1.z = P[q * 8 + 6][r]; o1.w = P[q * 8 + 7][r];
        *(float4*)&adjb[rowbase]     = o0;
        *(float4*)&adjb[rowbase + 4] = o1;
    }
}

// ---------------------------------------------------------------------------
extern "C" void kernel_launch(void* const* d_in, const int* in_sizes, int n_in,
                              void* d_out, int out_size, void* d_ws, size_t ws_size,
                              hipStream_t stream)
{
    const float* z   = (const float*)d_in[0];
    const float* W1  = (const float*)d_in[1];
    const float* b1  = (const float*)d_in[2];
    const float* W2  = (const float*)d_in[3];
    const float* b2  = (const float*)d_in[4];
    const float* E1  = (const float*)d_in[5];
    const float* eb1 = (const float*)d_in[6];
    const float* E2  = (const float*)d_in[7];
    const float* eb2 = (const float*)d_in[8];

    float* nodes_out = (float*)d_out;                                   // [32,512,8]
    float* adj       = (float*)d_out + BATCH * MAX_NODES * NODE_DIM;    // [32,512,512]

    unsigned int* UPKH = (unsigned int*)d_ws;       // 2 MB
    unsigned int* VHp  = UPKH + UPKH_DWORDS;        // 2 MB
    unsigned int* E2H  = VHp + VH_DWORDS;           // 128 B
    float*        Hws  = (float*)(E2H + 32);        // 16 KB

    h_gen<<<BATCH, 128, 0, stream>>>(z, W1, b1, Hws);

    dim3 g1(BATCH, 16);
    gen_nodes_uv<<<g1, 256, 0, stream>>>(Hws, W2, b2, E1, eb1, E2,
                                         nodes_out, UPKH, VHp, E2H);

    dim3 g2(72, BATCH);
    edge_gen<<<g2, 256, 0, stream>>>(UPKH, VHp, E2H, eb2, adj);
}